// Round 2
// baseline (5981.792 us; speedup 1.0000x reference)
//
#include <hip/hip_runtime.h>

#define N_NODES 100000
#define N_EDGES 3200000

// ---------------- degree / index prep ----------------

__global__ void k_init_deg(float* __restrict__ deg, int n) {
    int i = blockIdx.x * blockDim.x + threadIdx.x;
    if (i < n) deg[i] = 1.0f;  // self-loop contributes 1
}

// edge_index is int32: row 0 = src (ei[0..e)), row 1 = dst (ei[e..2e))
__global__ void k_count(const int* __restrict__ ei, float* __restrict__ deg, int e) {
    int i = blockIdx.x * blockDim.x + threadIdx.x;
    if (i < e) {
        int d = ei[e + i];
        if ((unsigned)d < (unsigned)N_NODES) atomicAdd(&deg[d], 1.0f);
    }
}

__global__ void k_dinv(float* __restrict__ deg, int n) {
    int i = blockIdx.x * blockDim.x + threadIdx.x;
    if (i < n) deg[i] = rsqrtf(deg[i]);  // deg >= 1 (self-loops)
}

// ---------------- dense: h_scaled = (x @ W) * dinv[row] ----------------

template <int IN, int OUT>
__global__ void k_gemm(const float* __restrict__ x, const float* __restrict__ W,
                       const float* __restrict__ dinv, float* __restrict__ h, int n) {
    // chunk K so the LDS tile stays <= 32 KB
    constexpr int KC = (IN * OUT * 4 > 32768) ? (IN / 2) : IN;
    __shared__ float Wl[KC * OUT];

    constexpr int NPB = 256 / OUT;  // nodes per block
    int node = blockIdx.x * NPB + (int)threadIdx.x / OUT;
    int o = (int)threadIdx.x % OUT;
    bool active = (node < n);
    const float* xr = x + (long long)(active ? node : 0) * IN;

    float acc = 0.0f;
    for (int kb = 0; kb < IN; kb += KC) {
        __syncthreads();
        for (int i = threadIdx.x; i < KC * OUT; i += blockDim.x)
            Wl[i] = W[kb * OUT + i];
        __syncthreads();
#pragma unroll
        for (int k = 0; k < KC; k += 4) {
            float4 xv = *(const float4*)(xr + kb + k);
            acc += xv.x * Wl[(k + 0) * OUT + o];
            acc += xv.y * Wl[(k + 1) * OUT + o];
            acc += xv.z * Wl[(k + 2) * OUT + o];
            acc += xv.w * Wl[(k + 3) * OUT + o];
        }
    }
    if (active) h[(long long)node * OUT + o] = acc * dinv[node];
}

// ---------------- copy (self-loop init): agg = h_scaled ----------------

__global__ void k_copy4(const float* __restrict__ src, float* __restrict__ dst, int n4) {
    int i = blockIdx.x * blockDim.x + threadIdx.x;
    if (i < n4) ((float4*)dst)[i] = ((const float4*)src)[i];
}

// ---------------- sparse: agg[dst] += h_scaled[src] ----------------

template <int D>
__global__ void k_scatter(const float* __restrict__ h, const int* __restrict__ ei,
                          float* __restrict__ agg, int e) {
    constexpr int V = D / 4;  // float4 groups per edge
    long long gid = (long long)blockIdx.x * blockDim.x + threadIdx.x;
    long long total = (long long)e * V;
    if (gid >= total) return;
    int edge = (int)(gid / V);
    int g = (int)(gid % V);
    int s = ei[edge];
    int d = ei[e + edge];
    if ((unsigned)s >= (unsigned)N_NODES || (unsigned)d >= (unsigned)N_NODES) return;
    float4 v = *(const float4*)(h + (long long)s * D + g * 4);
    float* a = agg + (long long)d * D + g * 4;
    atomicAdd(a + 0, v.x);
    atomicAdd(a + 1, v.y);
    atomicAdd(a + 2, v.z);
    atomicAdd(a + 3, v.w);
}

// ---------------- finalize: xout = relu(dinv*agg + b) ----------------

template <int D, bool RELU>
__global__ void k_finalize(const float* __restrict__ agg, const float* __restrict__ dinv,
                           const float* __restrict__ b, float* __restrict__ xout, int n) {
    int gid = blockIdx.x * blockDim.x + threadIdx.x;
    if (gid >= n * D) return;
    int node = gid / D;
    int o = gid % D;
    float v = dinv[node] * agg[gid] + b[o];
    if (RELU) v = fmaxf(v, 0.0f);
    xout[gid] = v;
}

// ---------------- final layer: out = log_softmax(dinv*agg + b) ----------------

__global__ void k_final4(const float* __restrict__ agg, const float* __restrict__ dinv,
                         const float* __restrict__ b, float* __restrict__ out, int n) {
    int i = blockIdx.x * blockDim.x + threadIdx.x;
    if (i >= n) return;
    float di = dinv[i];
    float4 v = *(const float4*)(agg + (long long)i * 4);
    float x0 = di * v.x + b[0];
    float x1 = di * v.y + b[1];
    float x2 = di * v.z + b[2];
    float x3 = di * v.w + b[3];
    float m = fmaxf(fmaxf(x0, x1), fmaxf(x2, x3));
    float s = expf(x0 - m) + expf(x1 - m) + expf(x2 - m) + expf(x3 - m);
    float ls = m + logf(s);
    float4 o = make_float4(x0 - ls, x1 - ls, x2 - ls, x3 - ls);
    *(float4*)(out + (long long)i * 4) = o;
}

// ---------------- launch ----------------

extern "C" void kernel_launch(void* const* d_in, const int* in_sizes, int n_in,
                              void* d_out, int out_size, void* d_ws, size_t ws_size,
                              hipStream_t stream) {
    const float* x = (const float*)d_in[0];
    const int* ei = (const int*)d_in[1];  // int32 [2, E]: row0=src, row1=dst
    const float* W1 = (const float*)d_in[2];
    const float* b1 = (const float*)d_in[3];
    const float* W2 = (const float*)d_in[4];
    const float* b2 = (const float*)d_in[5];
    const float* W3 = (const float*)d_in[6];
    const float* b3 = (const float*)d_in[7];
    const float* W4 = (const float*)d_in[8];
    const float* b4 = (const float*)d_in[9];
    float* out = (float*)d_out;

    const int n = N_NODES;
    const int e = N_EDGES;

    // workspace layout (16B-aligned), ~77 MB total
    char* ws = (char*)d_ws;
    size_t off = 0;
    auto alloc = [&](size_t bytes) {
        void* p = ws + off;
        off += (bytes + 255) & ~size_t(255);
        return p;
    };
    float* dinv = (float*)alloc((size_t)n * 4);
    float* A = (float*)alloc((size_t)n * 64 * 4);  // activations
    float* H = (float*)alloc((size_t)n * 64 * 4);  // gemm output (h_scaled)
    float* G = (float*)alloc((size_t)n * 64 * 4);  // aggregation buffer

    const int B = 256;

    // structure prep (shared by all 4 layers)
    k_init_deg<<<(n + B - 1) / B, B, 0, stream>>>(dinv, n);
    k_count<<<(e + B - 1) / B, B, 0, stream>>>(ei, dinv, e);
    k_dinv<<<(n + B - 1) / B, B, 0, stream>>>(dinv, n);

    // ---- layer 1: 256 -> 64, relu (reads external x, writes A) ----
    {
        constexpr int IN = 256, OUT = 64;
        k_gemm<IN, OUT><<<(n * OUT + B - 1) / B, B, 0, stream>>>(x, W1, dinv, H, n);
        int n4 = n * OUT / 4;
        k_copy4<<<(n4 + B - 1) / B, B, 0, stream>>>(H, G, n4);
        long long tot = (long long)e * (OUT / 4);
        k_scatter<OUT><<<(int)((tot + B - 1) / B), B, 0, stream>>>(H, ei, G, e);
        k_finalize<OUT, true><<<(n * OUT + B - 1) / B, B, 0, stream>>>(G, dinv, b1, A, n);
    }
    // ---- layer 2: 64 -> 32, relu ----
    {
        constexpr int IN = 64, OUT = 32;
        k_gemm<IN, OUT><<<(n * OUT + B - 1) / B, B, 0, stream>>>(A, W2, dinv, H, n);
        int n4 = n * OUT / 4;
        k_copy4<<<(n4 + B - 1) / B, B, 0, stream>>>(H, G, n4);
        long long tot = (long long)e * (OUT / 4);
        k_scatter<OUT><<<(int)((tot + B - 1) / B), B, 0, stream>>>(H, ei, G, e);
        k_finalize<OUT, true><<<(n * OUT + B - 1) / B, B, 0, stream>>>(G, dinv, b2, A, n);
    }
    // ---- layer 3: 32 -> 16, relu ----
    {
        constexpr int IN = 32, OUT = 16;
        k_gemm<IN, OUT><<<(n * OUT + B - 1) / B, B, 0, stream>>>(A, W3, dinv, H, n);
        int n4 = n * OUT / 4;
        k_copy4<<<(n4 + B - 1) / B, B, 0, stream>>>(H, G, n4);
        long long tot = (long long)e * (OUT / 4);
        k_scatter<OUT><<<(int)((tot + B - 1) / B), B, 0, stream>>>(H, ei, G, e);
        k_finalize<OUT, true><<<(n * OUT + B - 1) / B, B, 0, stream>>>(G, dinv, b3, A, n);
    }
    // ---- layer 4: 16 -> 4, log_softmax ----
    {
        constexpr int IN = 16, OUT = 4;
        k_gemm<IN, OUT><<<(n * OUT + B - 1) / B, B, 0, stream>>>(A, W4, dinv, H, n);
        int n4 = n * OUT / 4;
        k_copy4<<<(n4 + B - 1) / B, B, 0, stream>>>(H, G, n4);
        long long tot = (long long)e * (OUT / 4);
        k_scatter<OUT><<<(int)((tot + B - 1) / B), B, 0, stream>>>(H, ei, G, e);
        k_final4<<<(n + B - 1) / B, B, 0, stream>>>(G, dinv, b4, out, n);
    }
}

// Round 3
// 1437.904 us; speedup vs baseline: 4.1601x; 4.1601x over previous
//
#include <hip/hip_runtime.h>

#define N_NODES 100000
#define N_EDGES 3200000

// ======================= CSR build (once, structure shared) =======================

__global__ void k_zero_int(int* __restrict__ p, int n) {
    int i = blockIdx.x * blockDim.x + threadIdx.x;
    if (i < n) p[i] = 0;
}

// edge_index int32: row0 = src (ei[0..e)), row1 = dst (ei[e..2e))
__global__ void k_hist(const int* __restrict__ ei, int* __restrict__ cnt, int e) {
    int i = blockIdx.x * blockDim.x + threadIdx.x;
    if (i < e) {
        int d = ei[e + i];
        if ((unsigned)d < (unsigned)N_NODES) atomicAdd(&cnt[d], 1);
    }
}

__global__ void k_dinv_from_cnt(const int* __restrict__ cnt, float* __restrict__ dinv, int n) {
    int i = blockIdx.x * blockDim.x + threadIdx.x;
    if (i < n) dinv[i] = rsqrtf((float)(cnt[i] + 1));  // +1 self-loop
}

// exclusive scan: per-block Hillis-Steele, then scan partials, then add back
__global__ void k_scan_block(const int* __restrict__ cnt, int* __restrict__ excl,
                             int* __restrict__ partials, int n) {
    __shared__ int sm[256];
    int i = blockIdx.x * 256 + threadIdx.x;
    int v = (i < n) ? cnt[i] : 0;
    sm[threadIdx.x] = v;
    __syncthreads();
    for (int off = 1; off < 256; off <<= 1) {
        int t = (threadIdx.x >= off) ? sm[threadIdx.x - off] : 0;
        __syncthreads();
        sm[threadIdx.x] += t;
        __syncthreads();
    }
    if (i < n) excl[i] = sm[threadIdx.x] - v;
    if (threadIdx.x == 255) partials[blockIdx.x] = sm[255];
}

__global__ void k_scan_partials(int* __restrict__ partials, int m) {
    __shared__ int sm[512];
    int v = (threadIdx.x < m) ? partials[threadIdx.x] : 0;
    sm[threadIdx.x] = v;
    __syncthreads();
    for (int off = 1; off < 512; off <<= 1) {
        int t = (threadIdx.x >= off) ? sm[threadIdx.x - off] : 0;
        __syncthreads();
        sm[threadIdx.x] += t;
        __syncthreads();
    }
    if (threadIdx.x < m) partials[threadIdx.x] = sm[threadIdx.x] - v;  // exclusive
}

__global__ void k_scan_add(int* __restrict__ excl, const int* __restrict__ partials,
                           int* __restrict__ cursor, int n, int e) {
    int i = blockIdx.x * 256 + threadIdx.x;
    if (i < n) {
        int r = excl[i] + partials[blockIdx.x];
        excl[i] = r;
        cursor[i] = r;
    }
    if (i == 0) excl[n] = e;  // all dst valid (uniform in [0,N))
}

__global__ void k_fill(const int* __restrict__ ei, int* __restrict__ cursor,
                       int* __restrict__ col, int e) {
    int i = blockIdx.x * blockDim.x + threadIdx.x;
    if (i < e) {
        int s = ei[i];
        int d = ei[e + i];
        if ((unsigned)s >= (unsigned)N_NODES || (unsigned)d >= (unsigned)N_NODES) return;
        int p = atomicAdd(&cursor[d], 1);
        col[p] = s;
    }
}

// ======================= dense: h = (x @ W) * dinv[row] =======================

template <int IN, int OUT>
__global__ void k_gemm(const float* __restrict__ x, const float* __restrict__ W,
                       const float* __restrict__ dinv, float* __restrict__ h, int n) {
    constexpr int KC = (IN * OUT * 4 > 32768) ? (IN / 2) : IN;  // LDS tile <= 32 KB
    __shared__ float Wl[KC * OUT];

    constexpr int NPB = 256 / OUT;  // nodes per block
    int node = blockIdx.x * NPB + (int)threadIdx.x / OUT;
    int o = (int)threadIdx.x % OUT;
    bool active = (node < n);
    const float* xr = x + (long long)(active ? node : 0) * IN;

    float acc = 0.0f;
    for (int kb = 0; kb < IN; kb += KC) {
        __syncthreads();
        for (int i = threadIdx.x; i < KC * OUT; i += blockDim.x)
            Wl[i] = W[kb * OUT + i];
        __syncthreads();
#pragma unroll
        for (int k = 0; k < KC; k += 4) {
            float4 xv = *(const float4*)(xr + kb + k);
            acc += xv.x * Wl[(k + 0) * OUT + o];
            acc += xv.y * Wl[(k + 1) * OUT + o];
            acc += xv.z * Wl[(k + 2) * OUT + o];
            acc += xv.w * Wl[(k + 3) * OUT + o];
        }
    }
    if (active) h[(long long)node * OUT + o] = acc * dinv[node];
}

// ======================= sparse aggregate (CSR gather, no atomics) =======================
// MODE: 0 = relu, 2 = log_softmax (D==4)
template <int D, int MODE>
__global__ void k_aggregate(const float* __restrict__ h, const int* __restrict__ rp,
                            const int* __restrict__ col, const float* __restrict__ dinv,
                            const float* __restrict__ b, float* __restrict__ out, int n) {
    constexpr int GPW = 64 / D;  // node-groups per wave
    int wave = (int)(blockIdx.x * blockDim.x + threadIdx.x) >> 6;
    int lane = (int)threadIdx.x & 63;
    int grp = lane / D;
    int o = lane % D;
    int v = wave * GPW + grp;
    if (v >= n) return;

    float acc = h[(long long)v * D + o];  // self-loop
    int beg = rp[v], end = rp[v + 1];
    for (int i = beg; i < end; ++i) {
        int s = col[i];
        acc += h[(long long)s * D + o];
    }
    float val = dinv[v] * acc + b[o];

    if (MODE == 0) {
        out[(long long)v * D + o] = fmaxf(val, 0.0f);
    } else {
        // log_softmax across the D=4 group via shfl_xor (group base aligned to 4)
        float m = val;
        m = fmaxf(m, __shfl_xor(m, 1, 64));
        m = fmaxf(m, __shfl_xor(m, 2, 64));
        float ex = __expf(val - m);
        float s = ex;
        s += __shfl_xor(s, 1, 64);
        s += __shfl_xor(s, 2, 64);
        out[(long long)v * D + o] = val - (m + __logf(s));
    }
}

// ======================= launch =======================

extern "C" void kernel_launch(void* const* d_in, const int* in_sizes, int n_in,
                              void* d_out, int out_size, void* d_ws, size_t ws_size,
                              hipStream_t stream) {
    const float* x = (const float*)d_in[0];
    const int* ei = (const int*)d_in[1];  // int32 [2, E]
    const float* W1 = (const float*)d_in[2];
    const float* b1 = (const float*)d_in[3];
    const float* W2 = (const float*)d_in[4];
    const float* b2 = (const float*)d_in[5];
    const float* W3 = (const float*)d_in[6];
    const float* b3 = (const float*)d_in[7];
    const float* W4 = (const float*)d_in[8];
    const float* b4 = (const float*)d_in[9];
    float* out = (float*)d_out;

    const int n = N_NODES;
    const int e = N_EDGES;
    const int B = 256;
    const int nblk = (n + B - 1) / B;  // 391

    char* ws = (char*)d_ws;
    size_t off = 0;
    auto alloc = [&](size_t bytes) {
        void* p = ws + off;
        off += (bytes + 255) & ~size_t(255);
        return p;
    };
    float* dinv = (float*)alloc((size_t)n * 4);
    int* cnt = (int*)alloc((size_t)n * 4);
    int* rp = (int*)alloc((size_t)(n + 1) * 4);
    int* cursor = (int*)alloc((size_t)n * 4);
    int* partials = (int*)alloc((size_t)nblk * 4);
    int* col = (int*)alloc((size_t)e * 4);
    float* H = (float*)alloc((size_t)n * 64 * 4);
    float* A = (float*)alloc((size_t)n * 64 * 4);

    // ---- CSR build (once) ----
    k_zero_int<<<nblk, B, 0, stream>>>(cnt, n);
    k_hist<<<(e + B - 1) / B, B, 0, stream>>>(ei, cnt, e);
    k_dinv_from_cnt<<<nblk, B, 0, stream>>>(cnt, dinv, n);
    k_scan_block<<<nblk, B, 0, stream>>>(cnt, rp, partials, n);
    k_scan_partials<<<1, 512, 0, stream>>>(partials, nblk);
    k_scan_add<<<nblk, B, 0, stream>>>(rp, partials, cursor, n, e);
    k_fill<<<(e + B - 1) / B, B, 0, stream>>>(ei, cursor, col, e);

    // ---- layer 1: 256 -> 64, relu ----
    {
        constexpr int IN = 256, OUT = 64;
        k_gemm<IN, OUT><<<(n + (256 / OUT) - 1) / (256 / OUT), B, 0, stream>>>(x, W1, dinv, H, n);
        int npb = 4 * (64 / OUT);  // nodes per 256-thread block
        k_aggregate<OUT, 0><<<(n + npb - 1) / npb, B, 0, stream>>>(H, rp, col, dinv, b1, A, n);
    }
    // ---- layer 2: 64 -> 32, relu ----
    {
        constexpr int IN = 64, OUT = 32;
        k_gemm<IN, OUT><<<(n + (256 / OUT) - 1) / (256 / OUT), B, 0, stream>>>(A, W2, dinv, H, n);
        int npb = 4 * (64 / OUT);
        k_aggregate<OUT, 0><<<(n + npb - 1) / npb, B, 0, stream>>>(H, rp, col, dinv, b2, A, n);
    }
    // ---- layer 3: 32 -> 16, relu ----
    {
        constexpr int IN = 32, OUT = 16;
        k_gemm<IN, OUT><<<(n + (256 / OUT) - 1) / (256 / OUT), B, 0, stream>>>(A, W3, dinv, H, n);
        int npb = 4 * (64 / OUT);
        k_aggregate<OUT, 0><<<(n + npb - 1) / npb, B, 0, stream>>>(H, rp, col, dinv, b3, A, n);
    }
    // ---- layer 4: 16 -> 4, log_softmax ----
    {
        constexpr int IN = 16, OUT = 4;
        k_gemm<IN, OUT><<<(n + (256 / OUT) - 1) / (256 / OUT), B, 0, stream>>>(A, W4, dinv, H, n);
        int npb = 4 * (64 / OUT);
        k_aggregate<OUT, 2><<<(n + npb - 1) / npb, B, 0, stream>>>(H, rp, col, dinv, b4, out, n);
    }
}

// Round 4
// 1210.202 us; speedup vs baseline: 4.9428x; 1.1882x over previous
//
#include <hip/hip_runtime.h>

#define N_NODES 100000
#define N_EDGES 3200000

// ======================= CSR build (once, structure shared) =======================

__global__ void k_zero_int(int* __restrict__ p, int n) {
    int i = blockIdx.x * blockDim.x + threadIdx.x;
    if (i < n) p[i] = 0;
}

// edge_index int32: row0 = src (ei[0..e)), row1 = dst (ei[e..2e))
__global__ void k_hist(const int* __restrict__ ei, int* __restrict__ cnt, int e) {
    int i = blockIdx.x * blockDim.x + threadIdx.x;
    if (i < e) {
        int d = ei[e + i];
        if ((unsigned)d < (unsigned)N_NODES) atomicAdd(&cnt[d], 1);
    }
}

__global__ void k_dinv_from_cnt(const int* __restrict__ cnt, float* __restrict__ dinv, int n) {
    int i = blockIdx.x * blockDim.x + threadIdx.x;
    if (i < n) dinv[i] = rsqrtf((float)(cnt[i] + 1));  // +1 self-loop
}

// exclusive scan: per-block Hillis-Steele, then scan partials, then add back
__global__ void k_scan_block(const int* __restrict__ cnt, int* __restrict__ excl,
                             int* __restrict__ partials, int n) {
    __shared__ int sm[256];
    int i = blockIdx.x * 256 + threadIdx.x;
    int v = (i < n) ? cnt[i] : 0;
    sm[threadIdx.x] = v;
    __syncthreads();
    for (int off = 1; off < 256; off <<= 1) {
        int t = (threadIdx.x >= off) ? sm[threadIdx.x - off] : 0;
        __syncthreads();
        sm[threadIdx.x] += t;
        __syncthreads();
    }
    if (i < n) excl[i] = sm[threadIdx.x] - v;
    if (threadIdx.x == 255) partials[blockIdx.x] = sm[255];
}

__global__ void k_scan_partials(int* __restrict__ partials, int m) {
    __shared__ int sm[512];
    int v = (threadIdx.x < m) ? partials[threadIdx.x] : 0;
    sm[threadIdx.x] = v;
    __syncthreads();
    for (int off = 1; off < 512; off <<= 1) {
        int t = (threadIdx.x >= off) ? sm[threadIdx.x - off] : 0;
        __syncthreads();
        sm[threadIdx.x] += t;
        __syncthreads();
    }
    if (threadIdx.x < m) partials[threadIdx.x] = sm[threadIdx.x] - v;  // exclusive
}

__global__ void k_scan_add(int* __restrict__ excl, const int* __restrict__ partials,
                           int* __restrict__ cursor, int n, int e) {
    int i = blockIdx.x * 256 + threadIdx.x;
    if (i < n) {
        int r = excl[i] + partials[blockIdx.x];
        excl[i] = r;
        cursor[i] = r;
    }
    if (i == 0) excl[n] = e;  // all dst valid (uniform in [0,N))
}

__global__ void k_fill(const int* __restrict__ ei, int* __restrict__ cursor,
                       int* __restrict__ col, int e) {
    int i = blockIdx.x * blockDim.x + threadIdx.x;
    if (i < e) {
        int s = ei[i];
        int d = ei[e + i];
        if ((unsigned)s >= (unsigned)N_NODES || (unsigned)d >= (unsigned)N_NODES) return;
        int p = atomicAdd(&cursor[d], 1);
        col[p] = s;
    }
}

// ======================= dense: h = (x @ W) * dinv[row] =======================
// One wave per NPW nodes. lane = (slice s, output o), NS = 64/OUT slices give
// K-parallelism for small OUT. x rows read via wave-uniform pointer -> scalar
// loads; W chunk in per-lane VGPRs (coalesced, L2-resident).
template <int K, int OUT, int NPW>
__global__ void k_gemm(const float* __restrict__ x, const float* __restrict__ W,
                       const float* __restrict__ dinv, float* __restrict__ h, int n) {
    constexpr int NS = 64 / OUT;                      // k-slices per wave
    constexpr int KC = (K < 64 * NS) ? K : 64 * NS;   // k-chunk (w regs = KC/NS <= 64)
    constexpr int JW = KC / NS;                       // w registers per lane

    int tid = blockIdx.x * blockDim.x + threadIdx.x;
    int wid = __builtin_amdgcn_readfirstlane(tid >> 6);  // force SGPR (uniform)
    int lane = (int)threadIdx.x & 63;
    int o = lane % OUT;
    int s = lane / OUT;

    long long base = (long long)wid * NPW;
    if (base >= n) return;

    float acc[NPW];
#pragma unroll
    for (int m = 0; m < NPW; ++m) acc[m] = 0.0f;

    float w[JW];
    for (int kb = 0; kb < K; kb += KC) {
        const float* Wp = W + (long long)kb * OUT;
#pragma unroll
        for (int j = 0; j < JW; ++j) w[j] = Wp[j * 64 + lane];

#pragma unroll
        for (int m = 0; m < NPW; ++m) {
            const float* xr = x + (base + m) * K + kb;
            if constexpr (NS == 1) {
                // wave-uniform address -> s_load_dwordx4; SGPR * VGPR FMAs
#pragma unroll
                for (int j4 = 0; j4 < JW / 4; ++j4) {
                    float4 xv = *(const float4*)(xr + j4 * 4);
                    acc[m] = fmaf(xv.x, w[j4 * 4 + 0], acc[m]);
                    acc[m] = fmaf(xv.y, w[j4 * 4 + 1], acc[m]);
                    acc[m] = fmaf(xv.z, w[j4 * 4 + 2], acc[m]);
                    acc[m] = fmaf(xv.w, w[j4 * 4 + 3], acc[m]);
                }
            } else {
#pragma unroll
                for (int j = 0; j < JW; ++j)
                    acc[m] = fmaf(xr[j * NS + s], w[j], acc[m]);
            }
        }
    }

    if constexpr (NS > 1) {
#pragma unroll
        for (int m = 0; m < NPW; ++m)
#pragma unroll
            for (int off = OUT; off < 64; off <<= 1)
                acc[m] += __shfl_xor(acc[m], off, 64);
    }

    if (s == 0) {
#pragma unroll
        for (int m = 0; m < NPW; ++m) {
            long long v = base + m;
            if (v < n) h[v * OUT + o] = acc[m] * dinv[v];
        }
    }
}

// ======================= sparse aggregate (CSR gather, no atomics) =======================
// MODE: 0 = relu, 2 = log_softmax (D==4)
template <int D, int MODE>
__global__ void k_aggregate(const float* __restrict__ h, const int* __restrict__ rp,
                            const int* __restrict__ col, const float* __restrict__ dinv,
                            const float* __restrict__ b, float* __restrict__ out, int n) {
    constexpr int GPW = 64 / D;  // node-groups per wave
    int wave = (int)(blockIdx.x * blockDim.x + threadIdx.x) >> 6;
    int lane = (int)threadIdx.x & 63;
    int grp = lane / D;
    int o = lane % D;
    int v = wave * GPW + grp;
    if (v >= n) return;

    float acc = h[(long long)v * D + o];  // self-loop
    int beg = rp[v], end = rp[v + 1];
    for (int i = beg; i < end; ++i) {
        int s = col[i];
        acc += h[(long long)s * D + o];
    }
    float val = dinv[v] * acc + b[o];

    if (MODE == 0) {
        out[(long long)v * D + o] = fmaxf(val, 0.0f);
    } else {
        float m = val;
        m = fmaxf(m, __shfl_xor(m, 1, 64));
        m = fmaxf(m, __shfl_xor(m, 2, 64));
        float ex = __expf(val - m);
        float sum = ex;
        sum += __shfl_xor(sum, 1, 64);
        sum += __shfl_xor(sum, 2, 64);
        out[(long long)v * D + o] = val - (m + __logf(sum));
    }
}

// ======================= launch =======================

extern "C" void kernel_launch(void* const* d_in, const int* in_sizes, int n_in,
                              void* d_out, int out_size, void* d_ws, size_t ws_size,
                              hipStream_t stream) {
    const float* x = (const float*)d_in[0];
    const int* ei = (const int*)d_in[1];  // int32 [2, E]
    const float* W1 = (const float*)d_in[2];
    const float* b1 = (const float*)d_in[3];
    const float* W2 = (const float*)d_in[4];
    const float* b2 = (const float*)d_in[5];
    const float* W3 = (const float*)d_in[6];
    const float* b3 = (const float*)d_in[7];
    const float* W4 = (const float*)d_in[8];
    const float* b4 = (const float*)d_in[9];
    float* out = (float*)d_out;

    const int n = N_NODES;
    const int e = N_EDGES;
    const int B = 256;
    const int nblk = (n + B - 1) / B;  // 391

    char* ws = (char*)d_ws;
    size_t off = 0;
    auto alloc = [&](size_t bytes) {
        void* p = ws + off;
        off += (bytes + 255) & ~size_t(255);
        return p;
    };
    float* dinv = (float*)alloc((size_t)n * 4);
    int* cnt = (int*)alloc((size_t)n * 4);
    int* rp = (int*)alloc((size_t)(n + 1) * 4);
    int* cursor = (int*)alloc((size_t)n * 4);
    int* partials = (int*)alloc((size_t)nblk * 4);
    int* col = (int*)alloc((size_t)e * 4);
    float* H = (float*)alloc((size_t)n * 64 * 4);
    float* A = (float*)alloc((size_t)n * 64 * 4);

    // ---- CSR build (once) ----
    k_zero_int<<<nblk, B, 0, stream>>>(cnt, n);
    k_hist<<<(e + B - 1) / B, B, 0, stream>>>(ei, cnt, e);
    k_dinv_from_cnt<<<nblk, B, 0, stream>>>(cnt, dinv, n);
    k_scan_block<<<nblk, B, 0, stream>>>(cnt, rp, partials, n);
    k_scan_partials<<<1, 512, 0, stream>>>(partials, nblk);
    k_scan_add<<<nblk, B, 0, stream>>>(rp, partials, cursor, n, e);
    k_fill<<<(e + B - 1) / B, B, 0, stream>>>(ei, cursor, col, e);

    constexpr int NPW = 16;                      // nodes per wave (gemm)
    const int gwaves = (n + NPW - 1) / NPW;      // 6250
    const int gblk = (gwaves + 3) / 4;           // 4 waves per 256-thread block

    // ---- layer 1: 256 -> 64, relu ----
    {
        k_gemm<256, 64, NPW><<<gblk, B, 0, stream>>>(x, W1, dinv, H, n);
        int npb = 4 * (64 / 64);
        k_aggregate<64, 0><<<(n + npb - 1) / npb, B, 0, stream>>>(H, rp, col, dinv, b1, A, n);
    }
    // ---- layer 2: 64 -> 32, relu ----
    {
        k_gemm<64, 32, NPW><<<gblk, B, 0, stream>>>(A, W2, dinv, H, n);
        int npb = 4 * (64 / 32);
        k_aggregate<32, 0><<<(n + npb - 1) / npb, B, 0, stream>>>(H, rp, col, dinv, b2, A, n);
    }
    // ---- layer 3: 32 -> 16, relu ----
    {
        k_gemm<32, 16, NPW><<<gblk, B, 0, stream>>>(A, W3, dinv, H, n);
        int npb = 4 * (64 / 16);
        k_aggregate<16, 0><<<(n + npb - 1) / npb, B, 0, stream>>>(H, rp, col, dinv, b3, A, n);
    }
    // ---- layer 4: 16 -> 4, log_softmax ----
    {
        k_gemm<16, 4, NPW><<<gblk, B, 0, stream>>>(A, W4, dinv, H, n);
        int npb = 4 * (64 / 4);
        k_aggregate<4, 2><<<(n + npb - 1) / npb, B, 0, stream>>>(H, rp, col, dinv, b4, out, n);
    }
}

// Round 5
// 1032.747 us; speedup vs baseline: 5.7921x; 1.1718x over previous
//
#include <hip/hip_runtime.h>

#define N_NODES 100000
#define N_EDGES 3200000

// ======================= CSR build (once, structure shared) =======================

__global__ void k_zero_int(int* __restrict__ p, int n) {
    int i = blockIdx.x * blockDim.x + threadIdx.x;
    if (i < n) p[i] = 0;
}

// edge_index int32: row0 = src (ei[0..e)), row1 = dst (ei[e..2e))
__global__ void k_hist(const int* __restrict__ ei, int* __restrict__ cnt, int e) {
    int i = blockIdx.x * blockDim.x + threadIdx.x;
    if (i < e) {
        int d = ei[e + i];
        if ((unsigned)d < (unsigned)N_NODES) atomicAdd(&cnt[d], 1);
    }
}

__global__ void k_dinv_from_cnt(const int* __restrict__ cnt, float* __restrict__ dinv, int n) {
    int i = blockIdx.x * blockDim.x + threadIdx.x;
    if (i < n) dinv[i] = rsqrtf((float)(cnt[i] + 1));  // +1 self-loop
}

// exclusive scan: per-block Hillis-Steele, then scan partials, then add back
__global__ void k_scan_block(const int* __restrict__ cnt, int* __restrict__ excl,
                             int* __restrict__ partials, int n) {
    __shared__ int sm[256];
    int i = blockIdx.x * 256 + threadIdx.x;
    int v = (i < n) ? cnt[i] : 0;
    sm[threadIdx.x] = v;
    __syncthreads();
    for (int off = 1; off < 256; off <<= 1) {
        int t = (threadIdx.x >= off) ? sm[threadIdx.x - off] : 0;
        __syncthreads();
        sm[threadIdx.x] += t;
        __syncthreads();
    }
    if (i < n) excl[i] = sm[threadIdx.x] - v;
    if (threadIdx.x == 255) partials[blockIdx.x] = sm[255];
}

__global__ void k_scan_partials(int* __restrict__ partials, int m) {
    __shared__ int sm[512];
    int v = (threadIdx.x < m) ? partials[threadIdx.x] : 0;
    sm[threadIdx.x] = v;
    __syncthreads();
    for (int off = 1; off < 512; off <<= 1) {
        int t = (threadIdx.x >= off) ? sm[threadIdx.x - off] : 0;
        __syncthreads();
        sm[threadIdx.x] += t;
        __syncthreads();
    }
    if (threadIdx.x < m) partials[threadIdx.x] = sm[threadIdx.x] - v;  // exclusive
}

__global__ void k_scan_add(int* __restrict__ excl, const int* __restrict__ partials,
                           int* __restrict__ cursor, int n, int e) {
    int i = blockIdx.x * 256 + threadIdx.x;
    if (i < n) {
        int r = excl[i] + partials[blockIdx.x];
        excl[i] = r;
        cursor[i] = r;
    }
    if (i == 0) excl[n] = e;  // all dst valid (uniform in [0,N))
}

__global__ void k_fill(const int* __restrict__ ei, int* __restrict__ cursor,
                       int* __restrict__ col, int e) {
    int i = blockIdx.x * blockDim.x + threadIdx.x;
    if (i < e) {
        int s = ei[i];
        int d = ei[e + i];
        if ((unsigned)s >= (unsigned)N_NODES || (unsigned)d >= (unsigned)N_NODES) return;
        int p = atomicAdd(&cursor[d], 1);
        col[p] = s;
    }
}

// ======================= dense: h = (x @ W) * dinv[row] =======================
// LDS-tiled outer-product GEMM. Block = 64 nodes x OUT outs, 256 threads (16x16),
// per-thread 4 x (OUT/16) accumulators. xs staged transposed (pad->16B rows).
template <int K, int OUT, int BK>
__global__ __launch_bounds__(256) void k_gemm_tiled(const float* __restrict__ x,
                                                    const float* __restrict__ W,
                                                    const float* __restrict__ dinv,
                                                    float* __restrict__ h, int n) {
    constexpr int BM = 64;
    constexpr int TM = 4;
    constexpr int TN = OUT / 16;          // 4, 2, 1
    constexpr int PAD = 4;                // row stride 68 floats = 272 B (16B-aligned)
    __shared__ float xs[BK][BM + PAD];
    __shared__ float ws[BK][OUT];

    int t = (int)threadIdx.x;
    int tm = t >> 4;   // 0..15
    int tn = t & 15;   // 0..15
    int m0 = blockIdx.x * BM;

    float acc[TM][TN];
#pragma unroll
    for (int i = 0; i < TM; ++i)
#pragma unroll
        for (int j = 0; j < TN; ++j) acc[i][j] = 0.0f;

    for (int kb = 0; kb < K; kb += BK) {
        if (kb) __syncthreads();
        // ---- stage x tile, transposed ----
        constexpr int PER = (BM * BK) / (256 * 4);  // float4s per thread
#pragma unroll
        for (int f = 0; f < PER; ++f) {
            int flat = (f * 256 + t) * 4;
            int i = flat / BK;
            int j = flat % BK;
            int node = m0 + i;
            if (node >= n) node = n - 1;
            float4 v = *(const float4*)(x + (long long)node * K + kb + j);
            xs[j + 0][i] = v.x;
            xs[j + 1][i] = v.y;
            xs[j + 2][i] = v.z;
            xs[j + 3][i] = v.w;
        }
        // ---- stage W tile ----
        constexpr int WE = BK * OUT / 4;  // float4 count
        for (int f = t; f < WE; f += 256) {
            int flat = f * 4;
            int k = flat / OUT;
            int o = flat % OUT;
            *(float4*)&ws[k][o] = *(const float4*)&W[(long long)(kb + k) * OUT + o];
        }
        __syncthreads();

#pragma unroll 8
        for (int k = 0; k < BK; ++k) {
            float4 av = *(const float4*)&xs[k][tm * 4];
            float a[TM] = {av.x, av.y, av.z, av.w};
            float b[TN];
            if constexpr (TN == 4) {
                float4 bv = *(const float4*)&ws[k][tn * 4];
                b[0] = bv.x; b[1] = bv.y; b[2] = bv.z; b[3] = bv.w;
            } else if constexpr (TN == 2) {
                float2 bv = *(const float2*)&ws[k][tn * 2];
                b[0] = bv.x; b[1] = bv.y;
            } else {
                b[0] = ws[k][tn];
            }
#pragma unroll
            for (int i = 0; i < TM; ++i)
#pragma unroll
                for (int j = 0; j < TN; ++j)
                    acc[i][j] = fmaf(a[i], b[j], acc[i][j]);
        }
    }

    // ---- epilogue: h[node][o] = acc * dinv[node] ----
#pragma unroll
    for (int i = 0; i < TM; ++i) {
        int node = m0 + tm * 4 + i;
        if (node < n) {
            float di = dinv[node];
            float* hp = h + (long long)node * OUT + tn * TN;
#pragma unroll
            for (int j = 0; j < TN; ++j) hp[j] = acc[i][j] * di;
        }
    }
}

// per-wave gemm kept for the tiny final layer (K=16, OUT=4)
template <int K, int OUT, int NPW>
__global__ void k_gemm(const float* __restrict__ x, const float* __restrict__ W,
                       const float* __restrict__ dinv, float* __restrict__ h, int n) {
    constexpr int NS = 64 / OUT;
    constexpr int KC = (K < 64 * NS) ? K : 64 * NS;
    constexpr int JW = KC / NS;

    int tid = blockIdx.x * blockDim.x + threadIdx.x;
    int wid = __builtin_amdgcn_readfirstlane(tid >> 6);
    int lane = (int)threadIdx.x & 63;
    int o = lane % OUT;
    int s = lane / OUT;

    long long base = (long long)wid * NPW;
    if (base >= n) return;

    float acc[NPW];
#pragma unroll
    for (int m = 0; m < NPW; ++m) acc[m] = 0.0f;

    float w[JW];
    for (int kb = 0; kb < K; kb += KC) {
        const float* Wp = W + (long long)kb * OUT;
#pragma unroll
        for (int j = 0; j < JW; ++j) w[j] = Wp[j * 64 + lane];
#pragma unroll
        for (int m = 0; m < NPW; ++m) {
            const float* xr = x + (base + m) * K + kb;
#pragma unroll
            for (int j = 0; j < JW; ++j)
                acc[m] = fmaf(xr[j * NS + s], w[j], acc[m]);
        }
    }

#pragma unroll
    for (int m = 0; m < NPW; ++m)
#pragma unroll
        for (int off = OUT; off < 64; off <<= 1)
            acc[m] += __shfl_xor(acc[m], off, 64);

    if (s == 0) {
#pragma unroll
        for (int m = 0; m < NPW; ++m) {
            long long v = base + m;
            if (v < n) h[v * OUT + o] = acc[m] * dinv[v];
        }
    }
}

// ======================= sparse aggregate (CSR gather, no atomics) =======================
// MODE: 0 = relu, 2 = log_softmax (D==4)
template <int D, int MODE>
__global__ void k_aggregate(const float* __restrict__ h, const int* __restrict__ rp,
                            const int* __restrict__ col, const float* __restrict__ dinv,
                            const float* __restrict__ b, float* __restrict__ out, int n) {
    constexpr int GPW = 64 / D;  // node-groups per wave
    int wave = (int)(blockIdx.x * blockDim.x + threadIdx.x) >> 6;
    int lane = (int)threadIdx.x & 63;
    int grp = lane / D;
    int o = lane % D;
    int v = wave * GPW + grp;
    if (v >= n) return;

    float acc = h[(long long)v * D + o];  // self-loop
    int beg = rp[v], end = rp[v + 1];
    for (int i = beg; i < end; ++i) {
        int s = col[i];
        acc += h[(long long)s * D + o];
    }
    float val = dinv[v] * acc + b[o];

    if (MODE == 0) {
        out[(long long)v * D + o] = fmaxf(val, 0.0f);
    } else {
        float m = val;
        m = fmaxf(m, __shfl_xor(m, 1, 64));
        m = fmaxf(m, __shfl_xor(m, 2, 64));
        float ex = __expf(val - m);
        float sum = ex;
        sum += __shfl_xor(sum, 1, 64);
        sum += __shfl_xor(sum, 2, 64);
        out[(long long)v * D + o] = val - (m + __logf(sum));
    }
}

// ======================= launch =======================

extern "C" void kernel_launch(void* const* d_in, const int* in_sizes, int n_in,
                              void* d_out, int out_size, void* d_ws, size_t ws_size,
                              hipStream_t stream) {
    const float* x = (const float*)d_in[0];
    const int* ei = (const int*)d_in[1];  // int32 [2, E]
    const float* W1 = (const float*)d_in[2];
    const float* b1 = (const float*)d_in[3];
    const float* W2 = (const float*)d_in[4];
    const float* b2 = (const float*)d_in[5];
    const float* W3 = (const float*)d_in[6];
    const float* b3 = (const float*)d_in[7];
    const float* W4 = (const float*)d_in[8];
    const float* b4 = (const float*)d_in[9];
    float* out = (float*)d_out;

    const int n = N_NODES;
    const int e = N_EDGES;
    const int B = 256;
    const int nblk = (n + B - 1) / B;  // 391

    char* ws = (char*)d_ws;
    size_t off = 0;
    auto alloc = [&](size_t bytes) {
        void* p = ws + off;
        off += (bytes + 255) & ~size_t(255);
        return p;
    };
    float* dinv = (float*)alloc((size_t)n * 4);
    int* cnt = (int*)alloc((size_t)n * 4);
    int* rp = (int*)alloc((size_t)(n + 1) * 4);
    int* cursor = (int*)alloc((size_t)n * 4);
    int* partials = (int*)alloc((size_t)nblk * 4);
    int* col = (int*)alloc((size_t)e * 4);
    float* H = (float*)alloc((size_t)n * 64 * 4);
    float* A = (float*)alloc((size_t)n * 64 * 4);

    // ---- CSR build (once) ----
    k_zero_int<<<nblk, B, 0, stream>>>(cnt, n);
    k_hist<<<(e + B - 1) / B, B, 0, stream>>>(ei, cnt, e);
    k_dinv_from_cnt<<<nblk, B, 0, stream>>>(cnt, dinv, n);
    k_scan_block<<<nblk, B, 0, stream>>>(cnt, rp, partials, n);
    k_scan_partials<<<1, 512, 0, stream>>>(partials, nblk);
    k_scan_add<<<nblk, B, 0, stream>>>(rp, partials, cursor, n, e);
    k_fill<<<(e + B - 1) / B, B, 0, stream>>>(ei, cursor, col, e);

    const int gblk = (n + 63) / 64;  // tiled gemm blocks (BM=64)

    // ---- layer 1: 256 -> 64, relu ----
    {
        k_gemm_tiled<256, 64, 64><<<gblk, B, 0, stream>>>(x, W1, dinv, H, n);
        k_aggregate<64, 0><<<(n + 3) / 4, B, 0, stream>>>(H, rp, col, dinv, b1, A, n);
    }
    // ---- layer 2: 64 -> 32, relu ----
    {
        k_gemm_tiled<64, 32, 64><<<gblk, B, 0, stream>>>(A, W2, dinv, H, n);
        k_aggregate<32, 0><<<(n + 7) / 8, B, 0, stream>>>(H, rp, col, dinv, b2, A, n);
    }
    // ---- layer 3: 32 -> 16, relu ----
    {
        k_gemm_tiled<32, 16, 32><<<gblk, B, 0, stream>>>(A, W3, dinv, H, n);
        k_aggregate<16, 0><<<(n + 15) / 16, B, 0, stream>>>(H, rp, col, dinv, b3, A, n);
    }
    // ---- layer 4: 16 -> 4, log_softmax ----
    {
        constexpr int NPW = 16;
        const int g4 = ((n + NPW - 1) / NPW + 3) / 4;
        k_gemm<16, 4, NPW><<<g4, B, 0, stream>>>(A, W4, dinv, H, n);
        k_aggregate<4, 2><<<(n + 15) / 16, B, 0, stream>>>(H, rp, col, dinv, b4, out, n);
    }
}

// Round 6
// 742.888 us; speedup vs baseline: 8.0521x; 1.3902x over previous
//
#include <hip/hip_runtime.h>

#define N_NODES 100000
#define N_EDGES 3200000

// ======================= CSR build (once, structure shared) =======================

__global__ void k_zero_int(int* __restrict__ p, int n) {
    int i = blockIdx.x * blockDim.x + threadIdx.x;
    if (i < n) p[i] = 0;
}

// edge_index int32: row0 = src (ei[0..e)), row1 = dst (ei[e..2e))
__global__ void k_hist(const int* __restrict__ ei, int* __restrict__ cnt, int e) {
    int i = (blockIdx.x * blockDim.x + threadIdx.x) * 4;
    if (i + 3 < e) {
        int4 d4 = *(const int4*)(ei + e + i);
        if ((unsigned)d4.x < (unsigned)N_NODES) atomicAdd(&cnt[d4.x], 1);
        if ((unsigned)d4.y < (unsigned)N_NODES) atomicAdd(&cnt[d4.y], 1);
        if ((unsigned)d4.z < (unsigned)N_NODES) atomicAdd(&cnt[d4.z], 1);
        if ((unsigned)d4.w < (unsigned)N_NODES) atomicAdd(&cnt[d4.w], 1);
    } else {
        for (int k = i; k < e; ++k) {
            int d = ei[e + k];
            if ((unsigned)d < (unsigned)N_NODES) atomicAdd(&cnt[d], 1);
        }
    }
}

__global__ void k_dinv_from_cnt(const int* __restrict__ cnt, float* __restrict__ dinv, int n) {
    int i = blockIdx.x * blockDim.x + threadIdx.x;
    if (i < n) dinv[i] = rsqrtf((float)(cnt[i] + 1));  // +1 self-loop
}

// exclusive scan: per-block Hillis-Steele, then scan partials, then add back
__global__ void k_scan_block(const int* __restrict__ cnt, int* __restrict__ excl,
                             int* __restrict__ partials, int n) {
    __shared__ int sm[256];
    int i = blockIdx.x * 256 + threadIdx.x;
    int v = (i < n) ? cnt[i] : 0;
    sm[threadIdx.x] = v;
    __syncthreads();
    for (int off = 1; off < 256; off <<= 1) {
        int t = (threadIdx.x >= off) ? sm[threadIdx.x - off] : 0;
        __syncthreads();
        sm[threadIdx.x] += t;
        __syncthreads();
    }
    if (i < n) excl[i] = sm[threadIdx.x] - v;
    if (threadIdx.x == 255) partials[blockIdx.x] = sm[255];
}

__global__ void k_scan_partials(int* __restrict__ partials, int m) {
    __shared__ int sm[512];
    int v = (threadIdx.x < m) ? partials[threadIdx.x] : 0;
    sm[threadIdx.x] = v;
    __syncthreads();
    for (int off = 1; off < 512; off <<= 1) {
        int t = (threadIdx.x >= off) ? sm[threadIdx.x - off] : 0;
        __syncthreads();
        sm[threadIdx.x] += t;
        __syncthreads();
    }
    if (threadIdx.x < m) partials[threadIdx.x] = sm[threadIdx.x] - v;  // exclusive
}

__global__ void k_scan_add(int* __restrict__ excl, const int* __restrict__ partials,
                           int* __restrict__ cursor, int n, int e) {
    int i = blockIdx.x * 256 + threadIdx.x;
    if (i < n) {
        int r = excl[i] + partials[blockIdx.x];
        excl[i] = r;
        cursor[i] = r;
    }
    if (i == 0) excl[n] = e;  // all dst valid (uniform in [0,N))
}

__global__ void k_fill(const int* __restrict__ ei, int* __restrict__ cursor,
                       int* __restrict__ col, int e) {
    int i = blockIdx.x * blockDim.x + threadIdx.x;
    if (i < e) {
        int s = ei[i];
        int d = ei[e + i];
        if ((unsigned)s >= (unsigned)N_NODES || (unsigned)d >= (unsigned)N_NODES) return;
        int p = atomicAdd(&cursor[d], 1);
        col[p] = s;
    }
}

// ======================= dense: h = (x @ W) * dinv[row] =======================
// LDS-tiled outer-product GEMM. Block = 64 nodes x OUT outs, 256 threads (16x16),
// per-thread 4 x (OUT/16) accumulators. xs staged transposed (pad->16B rows).
template <int K, int OUT, int BK>
__global__ __launch_bounds__(256) void k_gemm_tiled(const float* __restrict__ x,
                                                    const float* __restrict__ W,
                                                    const float* __restrict__ dinv,
                                                    float* __restrict__ h, int n) {
    constexpr int BM = 64;
    constexpr int TM = 4;
    constexpr int TN = OUT / 16;          // 4, 2, 1
    constexpr int PAD = 4;                // row stride 68 floats = 272 B (16B-aligned)
    __shared__ float xs[BK][BM + PAD];
    __shared__ float ws[BK][OUT];

    int t = (int)threadIdx.x;
    int tm = t >> 4;   // 0..15
    int tn = t & 15;   // 0..15
    int m0 = blockIdx.x * BM;

    float acc[TM][TN];
#pragma unroll
    for (int i = 0; i < TM; ++i)
#pragma unroll
        for (int j = 0; j < TN; ++j) acc[i][j] = 0.0f;

    for (int kb = 0; kb < K; kb += BK) {
        if (kb) __syncthreads();
        // ---- stage x tile, transposed ----
        constexpr int PER = (BM * BK) / (256 * 4);  // float4s per thread
#pragma unroll
        for (int f = 0; f < PER; ++f) {
            int flat = (f * 256 + t) * 4;
            int i = flat / BK;
            int j = flat % BK;
            int node = m0 + i;
            if (node >= n) node = n - 1;
            float4 v = *(const float4*)(x + (long long)node * K + kb + j);
            xs[j + 0][i] = v.x;
            xs[j + 1][i] = v.y;
            xs[j + 2][i] = v.z;
            xs[j + 3][i] = v.w;
        }
        // ---- stage W tile ----
        constexpr int WE = BK * OUT / 4;  // float4 count
        for (int f = t; f < WE; f += 256) {
            int flat = f * 4;
            int k = flat / OUT;
            int o = flat % OUT;
            *(float4*)&ws[k][o] = *(const float4*)&W[(long long)(kb + k) * OUT + o];
        }
        __syncthreads();

#pragma unroll 8
        for (int k = 0; k < BK; ++k) {
            float4 av = *(const float4*)&xs[k][tm * 4];
            float a[TM] = {av.x, av.y, av.z, av.w};
            float b[TN];
            if constexpr (TN == 4) {
                float4 bv = *(const float4*)&ws[k][tn * 4];
                b[0] = bv.x; b[1] = bv.y; b[2] = bv.z; b[3] = bv.w;
            } else if constexpr (TN == 2) {
                float2 bv = *(const float2*)&ws[k][tn * 2];
                b[0] = bv.x; b[1] = bv.y;
            } else {
                b[0] = ws[k][tn];
            }
#pragma unroll
            for (int i = 0; i < TM; ++i)
#pragma unroll
                for (int j = 0; j < TN; ++j)
                    acc[i][j] = fmaf(a[i], b[j], acc[i][j]);
        }
    }

    // ---- epilogue: h[node][o] = acc * dinv[node] ----
#pragma unroll
    for (int i = 0; i < TM; ++i) {
        int node = m0 + tm * 4 + i;
        if (node < n) {
            float di = dinv[node];
            float* hp = h + (long long)node * OUT + tn * TN;
#pragma unroll
            for (int j = 0; j < TN; ++j) hp[j] = acc[i][j] * di;
        }
    }
}

// per-wave gemm kept for the tiny final layer (K=16, OUT=4)
template <int K, int OUT, int NPW>
__global__ void k_gemm(const float* __restrict__ x, const float* __restrict__ W,
                       const float* __restrict__ dinv, float* __restrict__ h, int n) {
    constexpr int NS = 64 / OUT;
    constexpr int KC = (K < 64 * NS) ? K : 64 * NS;
    constexpr int JW = KC / NS;

    int tid = blockIdx.x * blockDim.x + threadIdx.x;
    int wid = __builtin_amdgcn_readfirstlane(tid >> 6);
    int lane = (int)threadIdx.x & 63;
    int o = lane % OUT;
    int s = lane / OUT;

    long long base = (long long)wid * NPW;
    if (base >= n) return;

    float acc[NPW];
#pragma unroll
    for (int m = 0; m < NPW; ++m) acc[m] = 0.0f;

    float w[JW];
    for (int kb = 0; kb < K; kb += KC) {
        const float* Wp = W + (long long)kb * OUT;
#pragma unroll
        for (int j = 0; j < JW; ++j) w[j] = Wp[j * 64 + lane];
#pragma unroll
        for (int m = 0; m < NPW; ++m) {
            const float* xr = x + (base + m) * K + kb;
#pragma unroll
            for (int j = 0; j < JW; ++j)
                acc[m] = fmaf(xr[j * NS + s], w[j], acc[m]);
        }
    }

#pragma unroll
    for (int m = 0; m < NPW; ++m)
#pragma unroll
        for (int off = OUT; off < 64; off <<= 1)
            acc[m] += __shfl_xor(acc[m], off, 64);

    if (s == 0) {
#pragma unroll
        for (int m = 0; m < NPW; ++m) {
            long long v = base + m;
            if (v < n) h[v * OUT + o] = acc[m] * dinv[v];
        }
    }
}

// ======================= sparse aggregate (CSR gather, no atomics) =======================
// One wave per node. lane = (edge-group eg, quad o4): LPR = D/4 lanes read one
// h row as float4; EG = 64/LPR edges in flight per issue. Butterfly across eg
// groups, then val = (acc + self) * dinv + b; relu or in-lane log_softmax.
// MODE: 0 = relu, 2 = log_softmax (D==4)
template <int D, int MODE>
__global__ void k_aggregate(const float* __restrict__ h, const int* __restrict__ rp,
                            const int* __restrict__ col, const float* __restrict__ dinv,
                            const float* __restrict__ b, float* __restrict__ out, int n) {
    constexpr int LPR = D / 4;   // lanes per row (16, 8, 4, 1)
    constexpr int EG = 64 / LPR; // concurrent edges per wave (4, 8, 16, 64)

    int v = (int)((blockIdx.x * blockDim.x + threadIdx.x) >> 6);  // one node per wave
    if (v >= n) return;
    int lane = (int)threadIdx.x & 63;
    int eg = lane / LPR;
    int o4 = lane % LPR;

    int beg = rp[v], end = rp[v + 1];

    float4 acc = make_float4(0.f, 0.f, 0.f, 0.f);
    for (int i = beg + eg; i < end; i += EG) {
        int s = col[i];
        float4 hv = *(const float4*)(h + (long long)s * D + o4 * 4);
        acc.x += hv.x; acc.y += hv.y; acc.z += hv.z; acc.w += hv.w;
    }

    // reduce across edge-groups (same o4, different eg)
#pragma unroll
    for (int off = LPR; off < 64; off <<= 1) {
        acc.x += __shfl_xor(acc.x, off, 64);
        acc.y += __shfl_xor(acc.y, off, 64);
        acc.z += __shfl_xor(acc.z, off, 64);
        acc.w += __shfl_xor(acc.w, off, 64);
    }

    if (lane < LPR) {
        float4 self = *(const float4*)(h + (long long)v * D + o4 * 4);
        float4 bb = *(const float4*)(b + o4 * 4);
        float di = dinv[v];
        float4 val;
        val.x = di * (acc.x + self.x) + bb.x;
        val.y = di * (acc.y + self.y) + bb.y;
        val.z = di * (acc.z + self.z) + bb.z;
        val.w = di * (acc.w + self.w) + bb.w;

        if (MODE == 0) {
            val.x = fmaxf(val.x, 0.f); val.y = fmaxf(val.y, 0.f);
            val.z = fmaxf(val.z, 0.f); val.w = fmaxf(val.w, 0.f);
            *(float4*)(out + (long long)v * D + o4 * 4) = val;
        } else {
            // D == 4: all classes in this lane
            float m = fmaxf(fmaxf(val.x, val.y), fmaxf(val.z, val.w));
            float s0 = __expf(val.x - m) + __expf(val.y - m) +
                       __expf(val.z - m) + __expf(val.w - m);
            float ls = m + __logf(s0);
            *(float4*)(out + (long long)v * 4) =
                make_float4(val.x - ls, val.y - ls, val.z - ls, val.w - ls);
        }
    }
}

// ======================= launch =======================

extern "C" void kernel_launch(void* const* d_in, const int* in_sizes, int n_in,
                              void* d_out, int out_size, void* d_ws, size_t ws_size,
                              hipStream_t stream) {
    const float* x = (const float*)d_in[0];
    const int* ei = (const int*)d_in[1];  // int32 [2, E]
    const float* W1 = (const float*)d_in[2];
    const float* b1 = (const float*)d_in[3];
    const float* W2 = (const float*)d_in[4];
    const float* b2 = (const float*)d_in[5];
    const float* W3 = (const float*)d_in[6];
    const float* b3 = (const float*)d_in[7];
    const float* W4 = (const float*)d_in[8];
    const float* b4 = (const float*)d_in[9];
    float* out = (float*)d_out;

    const int n = N_NODES;
    const int e = N_EDGES;
    const int B = 256;
    const int nblk = (n + B - 1) / B;  // 391

    char* ws = (char*)d_ws;
    size_t off = 0;
    auto alloc = [&](size_t bytes) {
        void* p = ws + off;
        off += (bytes + 255) & ~size_t(255);
        return p;
    };
    float* dinv = (float*)alloc((size_t)n * 4);
    int* cnt = (int*)alloc((size_t)n * 4);
    int* rp = (int*)alloc((size_t)(n + 1) * 4);
    int* cursor = (int*)alloc((size_t)n * 4);
    int* partials = (int*)alloc((size_t)nblk * 4);
    int* col = (int*)alloc((size_t)e * 4);
    float* H = (float*)alloc((size_t)n * 64 * 4);
    float* A = (float*)alloc((size_t)n * 64 * 4);

    // ---- CSR build (once) ----
    k_zero_int<<<nblk, B, 0, stream>>>(cnt, n);
    k_hist<<<(e / 4 + B - 1) / B, B, 0, stream>>>(ei, cnt, e);
    k_dinv_from_cnt<<<nblk, B, 0, stream>>>(cnt, dinv, n);
    k_scan_block<<<nblk, B, 0, stream>>>(cnt, rp, partials, n);
    k_scan_partials<<<1, 512, 0, stream>>>(partials, nblk);
    k_scan_add<<<nblk, B, 0, stream>>>(rp, partials, cursor, n, e);
    k_fill<<<(e + B - 1) / B, B, 0, stream>>>(ei, cursor, col, e);

    const int gblk = (n + 63) / 64;   // tiled gemm blocks (BM=64)
    const int ablk = (n + 3) / 4;     // aggregate blocks (4 waves = 4 nodes / block)

    // ---- layer 1: 256 -> 64, relu ----
    {
        k_gemm_tiled<256, 64, 64><<<gblk, B, 0, stream>>>(x, W1, dinv, H, n);
        k_aggregate<64, 0><<<ablk, B, 0, stream>>>(H, rp, col, dinv, b1, A, n);
    }
    // ---- layer 2: 64 -> 32, relu ----
    {
        k_gemm_tiled<64, 32, 64><<<gblk, B, 0, stream>>>(A, W2, dinv, H, n);
        k_aggregate<32, 0><<<ablk, B, 0, stream>>>(H, rp, col, dinv, b2, A, n);
    }
    // ---- layer 3: 32 -> 16, relu ----
    {
        k_gemm_tiled<32, 16, 32><<<gblk, B, 0, stream>>>(A, W3, dinv, H, n);
        k_aggregate<16, 0><<<ablk, B, 0, stream>>>(H, rp, col, dinv, b3, A, n);
    }
    // ---- layer 4: 16 -> 4, log_softmax ----
    {
        constexpr int NPW = 16;
        const int g4 = ((n + NPW - 1) / NPW + 3) / 4;
        k_gemm<16, 4, NPW><<<g4, B, 0, stream>>>(A, W4, dinv, H, n);
        k_aggregate<4, 2><<<ablk, B, 0, stream>>>(H, rp, col, dinv, b4, out, n);
    }
}